// Round 1
// baseline (2115.152 us; speedup 1.0000x reference)
//
#include <hip/hip_runtime.h>

#define N_NODES 200000
#define E_EVENTS 1000000
#define D_DIM 128
#define B_BATCH 50000
#define K_NEI 20

// ---------------------------------------------------------------------------
// Kernel 1: segment accumulate (sum of message, count, max timestamp) via atomics.
// 32 threads per event; each thread loads one float4 of the 128-dim message.
// ---------------------------------------------------------------------------
__global__ void seg_accum(const int* __restrict__ node_ids,
                          const float* __restrict__ message,
                          const float* __restrict__ ts,
                          float* __restrict__ msg_sum,   // [N,128], pre-zeroed
                          float* __restrict__ counts,    // [N], pre-zeroed
                          int* __restrict__ tmax)        // [N] float bits, pre-zeroed
{
    int tid  = blockIdx.x * blockDim.x + threadIdx.x;
    int e    = tid >> 5;
    int lane = tid & 31;
    if (e >= E_EVENTS) return;
    int n = node_ids[e];
    float4 m = reinterpret_cast<const float4*>(message)[(size_t)e * 32 + lane];
    float* dst = msg_sum + (size_t)n * D_DIM + lane * 4;
    atomicAdd(dst + 0, m.x);
    atomicAdd(dst + 1, m.y);
    atomicAdd(dst + 2, m.z);
    atomicAdd(dst + 3, m.w);
    if (lane == 0) {
        atomicAdd(counts + n, 1.0f);
        // timestamps are uniform[0,1): non-negative, so int-compare == float-compare
        atomicMax(tmax + n, __float_as_int(ts[e]));
    }
}

// ---------------------------------------------------------------------------
// Kernel 2: divide each node's message sum by max(count,1)  (segment mean).
// float4 per thread.
// ---------------------------------------------------------------------------
__global__ void seg_finalize(float4* __restrict__ msg, const float* __restrict__ counts)
{
    int i = blockIdx.x * blockDim.x + threadIdx.x;   // over N*32
    if (i >= N_NODES * 32) return;
    int n = i >> 5;
    float inv = 1.0f / fmaxf(counts[n], 1.0f);
    float4 v = msg[i];
    v.x *= inv; v.y *= inv; v.z *= inv; v.w *= inv;
    msg[i] = v;
}

// ---------------------------------------------------------------------------
// Kernel 3: attention logits. One wave (64 lanes) per batch element b.
// s[d] = sum_k nei2[b,k,d]; logits[b,k] = dot(nei1[b,k,:], s).
// Lane owns dims (lane, lane+64).
// ---------------------------------------------------------------------------
__global__ void attn_logits(const float* __restrict__ nei1,
                            const float* __restrict__ nei2,
                            float* __restrict__ logits)   // [B,K]
{
    int b = blockIdx.x;
    int lane = threadIdx.x;   // 0..63
    const float* n2 = nei2 + (size_t)b * K_NEI * D_DIM;
    float s0 = 0.f, s1 = 0.f;
#pragma unroll
    for (int k = 0; k < K_NEI; ++k) {
        s0 += n2[k * D_DIM + lane];
        s1 += n2[k * D_DIM + lane + 64];
    }
    const float* n1 = nei1 + (size_t)b * K_NEI * D_DIM;
#pragma unroll
    for (int k = 0; k < K_NEI; ++k) {
        float p = n1[k * D_DIM + lane] * s0 + n1[k * D_DIM + lane + 64] * s1;
#pragma unroll
        for (int off = 32; off; off >>= 1) p += __shfl_down(p, off);
        if (lane == 0) logits[(size_t)b * K_NEI + k] = p;
    }
}

// ---------------------------------------------------------------------------
// Kernel 4: per-column (k) softmax stats over dim 0 (b = 0..B-1).
// One block per column: pass 1 max, pass 2 sum of exp.
// ---------------------------------------------------------------------------
__global__ void col_stats(const float* __restrict__ logits, float2* __restrict__ stats)
{
    int k = blockIdx.x;
    int t = threadIdx.x;            // 256 threads = 4 waves
    __shared__ float wm[4], ws[4];

    float m = -INFINITY;
    for (int b = t; b < B_BATCH; b += blockDim.x)
        m = fmaxf(m, logits[(size_t)b * K_NEI + k]);
#pragma unroll
    for (int off = 32; off; off >>= 1) m = fmaxf(m, __shfl_down(m, off));
    if ((t & 63) == 0) wm[t >> 6] = m;
    __syncthreads();
    float bm = fmaxf(fmaxf(wm[0], wm[1]), fmaxf(wm[2], wm[3]));

    float s = 0.f;
    for (int b = t; b < B_BATCH; b += blockDim.x)
        s += expf(logits[(size_t)b * K_NEI + k] - bm);
#pragma unroll
    for (int off = 32; off; off >>= 1) s += __shfl_down(s, off);
    if ((t & 63) == 0) ws[t >> 6] = s;
    __syncthreads();
    if (t == 0) stats[k] = make_float2(bm, ws[0] + ws[1] + ws[2] + ws[3]);
}

// ---------------------------------------------------------------------------
// Kernel 5: normalize logits in place -> softmax scores.
// ---------------------------------------------------------------------------
__global__ void softmax_norm(float* __restrict__ score, const float2* __restrict__ stats)
{
    int i = blockIdx.x * blockDim.x + threadIdx.x;
    if (i >= B_BATCH * K_NEI) return;
    int k = i % K_NEI;
    float2 st = stats[k];
    score[i] = expf(score[i] - st.x) / st.y;
}

extern "C" void kernel_launch(void* const* d_in, const int* in_sizes, int n_in,
                              void* d_out, int out_size, void* d_ws, size_t ws_size,
                              hipStream_t stream)
{
    const int*   node_ids = (const int*)  d_in[0];
    const float* message  = (const float*)d_in[1];
    const float* ts       = (const float*)d_in[2];
    const float* nei1     = (const float*)d_in[3];
    const float* nei2     = (const float*)d_in[4];

    float* out     = (float*)d_out;
    float* msg_out = out;                                   // [N,128]
    float* t_out   = out + (size_t)N_NODES * D_DIM;         // [N]
    float* score   = t_out + N_NODES;                       // [B,K]

    float*  counts = (float*)d_ws;                          // [N]
    float2* stats  = (float2*)((char*)d_ws + (size_t)N_NODES * sizeof(float)); // [K]

    // zero the accumulator regions (d_out is poisoned; ws not re-poisoned between replays)
    hipMemsetAsync(msg_out, 0, ((size_t)N_NODES * D_DIM + N_NODES) * sizeof(float), stream);
    hipMemsetAsync(counts,  0, (size_t)N_NODES * sizeof(float), stream);

    seg_accum<<<(E_EVENTS * 32) / 256, 256, 0, stream>>>(
        node_ids, message, ts, msg_out, counts, (int*)t_out);

    seg_finalize<<<(N_NODES * 32 + 255) / 256, 256, 0, stream>>>(
        (float4*)msg_out, counts);

    attn_logits<<<B_BATCH, 64, 0, stream>>>(nei1, nei2, score);

    col_stats<<<K_NEI, 256, 0, stream>>>(score, stats);

    softmax_norm<<<(B_BATCH * K_NEI + 255) / 256, 256, 0, stream>>>(score, stats);
}

// Round 2
// 568.434 us; speedup vs baseline: 3.7210x; 3.7210x over previous
//
#include <hip/hip_runtime.h>

#define N_NODES 200000
#define E_EVENTS 1000000
#define D_DIM 128
#define B_BATCH 50000
#define K_NEI 20

#define SCAN_BLK 196              // ceil(200000/1024)

// ---------------- ws layout (element offsets, 4B units) --------------------
// counts   : [0,        200000)   int
// offsets  : [200000,   400000)   int
// cursor   : [400000,   600000)   int
// blockSums: [600000,   600256)   int
// perm     : [600320,  1600320)   int
// stats    : [1600320, 1600360)   float2[20]
// partials : [1600384, 1605504)   float2[128*20]

// ---------------------------------------------------------------------------
// 1) histogram of node ids
// ---------------------------------------------------------------------------
__global__ void hist(const int* __restrict__ ids, int* __restrict__ counts)
{
    int e = blockIdx.x * blockDim.x + threadIdx.x;
    if (e < E_EVENTS) atomicAdd(counts + ids[e], 1);
}

// ---------------------------------------------------------------------------
// 2) per-block sums (1024 counts per block)
// ---------------------------------------------------------------------------
__global__ void scan_block(const int* __restrict__ counts, int* __restrict__ blockSums)
{
    __shared__ int sd[256];
    int t = threadIdx.x, base = blockIdx.x * 1024 + t * 4;
    int s = 0;
#pragma unroll
    for (int j = 0; j < 4; ++j) { int i = base + j; if (i < N_NODES) s += counts[i]; }
    sd[t] = s; __syncthreads();
    for (int off = 128; off; off >>= 1) {
        if (t < off) sd[t] += sd[t + off];
        __syncthreads();
    }
    if (t == 0) blockSums[blockIdx.x] = sd[0];
}

// ---------------------------------------------------------------------------
// 3) exclusive scan of block sums (tiny, single thread)
// ---------------------------------------------------------------------------
__global__ void scan_tops(int* __restrict__ blockSums)
{
    if (threadIdx.x == 0 && blockIdx.x == 0) {
        int run = 0;
        for (int i = 0; i < SCAN_BLK; ++i) { int v = blockSums[i]; blockSums[i] = run; run += v; }
    }
}

// ---------------------------------------------------------------------------
// 4) final scan: per-block exclusive scan + block offset -> offsets, cursor
// ---------------------------------------------------------------------------
__global__ void scan_final(const int* __restrict__ counts, const int* __restrict__ blockSums,
                           int* __restrict__ offsets, int* __restrict__ cursor)
{
    __shared__ int sd[256];
    int t = threadIdx.x, base = blockIdx.x * 1024 + t * 4;
    int c[4];
#pragma unroll
    for (int j = 0; j < 4; ++j) { int i = base + j; c[j] = (i < N_NODES) ? counts[i] : 0; }
    int tsum = c[0] + c[1] + c[2] + c[3];
    sd[t] = tsum; __syncthreads();
    // inclusive Hillis-Steele over 256 thread sums
    for (int off = 1; off < 256; off <<= 1) {
        int x = (t >= off) ? sd[t - off] : 0;
        __syncthreads();
        sd[t] += x;
        __syncthreads();
    }
    int excl = sd[t] - tsum + blockSums[blockIdx.x];
#pragma unroll
    for (int j = 0; j < 4; ++j) {
        int i = base + j;
        if (i < N_NODES) { offsets[i] = excl; cursor[i] = excl; }
        excl += c[j];
    }
}

// ---------------------------------------------------------------------------
// 5) scatter event indices into CSR order
// ---------------------------------------------------------------------------
__global__ void scatter(const int* __restrict__ ids, int* __restrict__ cursor,
                        int* __restrict__ perm)
{
    int e = blockIdx.x * blockDim.x + threadIdx.x;
    if (e < E_EVENTS) {
        int pos = atomicAdd(cursor + ids[e], 1);
        perm[pos] = e;
    }
}

// ---------------------------------------------------------------------------
// 6) gather-reduce: one wave per node. Lane owns 2 dims (float2).
//    Computes mean message and max timestamp; empty segments -> 0.
// ---------------------------------------------------------------------------
__global__ void seg_reduce(const int* __restrict__ perm, const int* __restrict__ offsets,
                           const int* __restrict__ counts,
                           const float* __restrict__ message, const float* __restrict__ ts,
                           float* __restrict__ msg_out, float* __restrict__ t_out)
{
    int wid  = threadIdx.x >> 6;
    int lane = threadIdx.x & 63;
    int n = blockIdx.x * 4 + wid;
    if (n >= N_NODES) return;
    int start = offsets[n];
    int len   = counts[n];
    const float2* msg2 = reinterpret_cast<const float2*>(message);
    float2 acc = make_float2(0.f, 0.f);
    float tmax = 0.f;
    for (int i = 0; i < len; ++i) {
        int e = perm[start + i];
        float2 m = msg2[(size_t)e * 64 + lane];
        acc.x += m.x; acc.y += m.y;
        tmax = fmaxf(tmax, ts[e]);
    }
    float inv = 1.0f / (float)max(len, 1);
    acc.x *= inv; acc.y *= inv;
    reinterpret_cast<float2*>(msg_out)[(size_t)n * 64 + lane] = acc;
    if (lane == 0) t_out[n] = tmax;
}

// ---------------------------------------------------------------------------
// 7) attention logits, float4. One wave per b, 4 waves per block.
//    lane = half*32 + d4: half selects k parity, d4 selects float4 chunk.
// ---------------------------------------------------------------------------
__global__ void attn_logits(const float* __restrict__ nei1,
                            const float* __restrict__ nei2,
                            float* __restrict__ logits)
{
    int wid  = threadIdx.x >> 6;
    int lane = threadIdx.x & 63;
    int b = blockIdx.x * 4 + wid;           // grid exactly covers B
    int d4   = lane & 31;
    int half = lane >> 5;
    const float4* n2 = reinterpret_cast<const float4*>(nei2) + (size_t)b * (K_NEI * 32);
    float4 acc = make_float4(0.f, 0.f, 0.f, 0.f);
#pragma unroll
    for (int i = 0; i < K_NEI / 2; ++i) {
        float4 v = n2[(2 * i + half) * 32 + d4];
        acc.x += v.x; acc.y += v.y; acc.z += v.z; acc.w += v.w;
    }
    // combine the two k-parity halves: s4 = full sum over k for this d4 chunk
    float4 s4;
    s4.x = acc.x + __shfl_xor(acc.x, 32);
    s4.y = acc.y + __shfl_xor(acc.y, 32);
    s4.z = acc.z + __shfl_xor(acc.z, 32);
    s4.w = acc.w + __shfl_xor(acc.w, 32);

    const float4* n1 = reinterpret_cast<const float4*>(nei1) + (size_t)b * (K_NEI * 32);
#pragma unroll
    for (int i = 0; i < K_NEI / 2; ++i) {
        int k = 2 * i + half;
        float4 v = n1[k * 32 + d4];
        float p = v.x * s4.x + v.y * s4.y + v.z * s4.z + v.w * s4.w;
#pragma unroll
        for (int off = 16; off; off >>= 1) p += __shfl_xor(p, off);  // within 32-half
        if (d4 == 0) logits[(size_t)b * K_NEI + k] = p;
    }
}

// ---------------------------------------------------------------------------
// 8) per-block online softmax partials over dim 0 (b). 128 blocks.
// ---------------------------------------------------------------------------
__global__ void softmax_partial(const float* __restrict__ logits, float2* __restrict__ partials)
{
    int t = threadIdx.x;
    float m[K_NEI], s[K_NEI];
#pragma unroll
    for (int k = 0; k < K_NEI; ++k) { m[k] = -INFINITY; s[k] = 0.f; }

    for (int b = blockIdx.x * 256 + t; b < B_BATCH; b += 128 * 256) {
        const float4* row = reinterpret_cast<const float4*>(logits + (size_t)b * K_NEI);
        float v[K_NEI];
#pragma unroll
        for (int q = 0; q < 5; ++q) {
            float4 r = row[q];
            v[q * 4 + 0] = r.x; v[q * 4 + 1] = r.y; v[q * 4 + 2] = r.z; v[q * 4 + 3] = r.w;
        }
#pragma unroll
        for (int k = 0; k < K_NEI; ++k) {
            float nm = fmaxf(m[k], v[k]);
            s[k] = s[k] * expf(m[k] - nm) + expf(v[k] - nm);
            m[k] = nm;
        }
    }
    // wave-level merge
#pragma unroll
    for (int k = 0; k < K_NEI; ++k) {
#pragma unroll
        for (int off = 32; off; off >>= 1) {
            float om = __shfl_xor(m[k], off);
            float os = __shfl_xor(s[k], off);
            float nm = fmaxf(m[k], om);
            s[k] = s[k] * expf(m[k] - nm) + os * expf(om - nm);
            m[k] = nm;
        }
    }
    __shared__ float lm[4][K_NEI], lsum[4][K_NEI];
    int wid = t >> 6, lane = t & 63;
    if (lane == 0) {
#pragma unroll
        for (int k = 0; k < K_NEI; ++k) { lm[wid][k] = m[k]; lsum[wid][k] = s[k]; }
    }
    __syncthreads();
    if (t < K_NEI) {
        float mm = lm[0][t], ss = lsum[0][t];
#pragma unroll
        for (int w = 1; w < 4; ++w) {
            float om = lm[w][t], os = lsum[w][t];
            float nm = fmaxf(mm, om);
            ss = ss * expf(mm - nm) + os * expf(om - nm);
            mm = nm;
        }
        partials[blockIdx.x * K_NEI + t] = make_float2(mm, ss);
    }
}

// ---------------------------------------------------------------------------
// 9) combine 128 partials -> stats[k]
// ---------------------------------------------------------------------------
__global__ void softmax_final(const float2* __restrict__ partials, float2* __restrict__ stats)
{
    int t = threadIdx.x;
    if (t < K_NEI) {
        float mm = -INFINITY, ss = 0.f;
        for (int i = 0; i < 128; ++i) {
            float2 p = partials[i * K_NEI + t];
            float nm = fmaxf(mm, p.x);
            ss = ss * expf(mm - nm) + p.y * expf(p.x - nm);
            mm = nm;
        }
        stats[t] = make_float2(mm, ss);
    }
}

// ---------------------------------------------------------------------------
// 10) normalize logits -> softmax scores
// ---------------------------------------------------------------------------
__global__ void softmax_norm(float* __restrict__ score, const float2* __restrict__ stats)
{
    int i = blockIdx.x * blockDim.x + threadIdx.x;
    if (i >= B_BATCH * K_NEI) return;
    int k = i % K_NEI;
    float2 st = stats[k];
    score[i] = expf(score[i] - st.x) / st.y;
}

extern "C" void kernel_launch(void* const* d_in, const int* in_sizes, int n_in,
                              void* d_out, int out_size, void* d_ws, size_t ws_size,
                              hipStream_t stream)
{
    const int*   node_ids = (const int*)  d_in[0];
    const float* message  = (const float*)d_in[1];
    const float* ts       = (const float*)d_in[2];
    const float* nei1     = (const float*)d_in[3];
    const float* nei2     = (const float*)d_in[4];

    float* out     = (float*)d_out;
    float* msg_out = out;                                   // [N,128]
    float* t_out   = out + (size_t)N_NODES * D_DIM;         // [N]
    float* score   = t_out + N_NODES;                       // [B,K]

    int*    wsi       = (int*)d_ws;
    int*    counts    = wsi;
    int*    offsets   = wsi + 200000;
    int*    cursor    = wsi + 400000;
    int*    blockSums = wsi + 600000;
    int*    perm      = wsi + 600320;
    float2* stats     = (float2*)(wsi + 1600320);
    float2* partials  = (float2*)(wsi + 1600384);

    hipMemsetAsync(counts, 0, (size_t)N_NODES * sizeof(int), stream);

    hist<<<(E_EVENTS + 255) / 256, 256, 0, stream>>>(node_ids, counts);
    scan_block<<<SCAN_BLK, 256, 0, stream>>>(counts, blockSums);
    scan_tops<<<1, 64, 0, stream>>>(blockSums);
    scan_final<<<SCAN_BLK, 256, 0, stream>>>(counts, blockSums, offsets, cursor);
    scatter<<<(E_EVENTS + 255) / 256, 256, 0, stream>>>(node_ids, cursor, perm);

    seg_reduce<<<(N_NODES + 3) / 4, 256, 0, stream>>>(
        perm, offsets, counts, message, ts, msg_out, t_out);

    attn_logits<<<B_BATCH / 4, 256, 0, stream>>>(nei1, nei2, score);

    softmax_partial<<<128, 256, 0, stream>>>(score, partials);
    softmax_final<<<1, 64, 0, stream>>>(partials, stats);
    softmax_norm<<<(B_BATCH * K_NEI + 255) / 256, 256, 0, stream>>>(score, stats);
}

// Round 3
// 476.257 us; speedup vs baseline: 4.4412x; 1.1935x over previous
//
#include <hip/hip_runtime.h>

#define N_NODES 200000
#define E_EVENTS 1000000
#define D_DIM 128
#define B_BATCH 50000
#define K_NEI 20

#define SCAN_BLK 196              // ceil(200000/1024)

// ---------------- ws layout (element offsets, 4B units) --------------------
// counts   : [0,        200000)   int
// offsets  : [200000,   400000)   int
// cursor   : [400000,   600000)   int
// blockSums: [600000,   600256)   int
// perm     : [600320,  1600320)   int
// stats    : [1600320, 1600360)   float2[20]
// partials : [1600384, 1605504)   float2[128*20]

// ---------------------------------------------------------------------------
// 1) histogram of node ids
// ---------------------------------------------------------------------------
__global__ void hist(const int* __restrict__ ids, int* __restrict__ counts)
{
    int e = blockIdx.x * blockDim.x + threadIdx.x;
    if (e < E_EVENTS) atomicAdd(counts + ids[e], 1);
}

// ---------------------------------------------------------------------------
// 2) per-block sums (1024 counts per block)
// ---------------------------------------------------------------------------
__global__ void scan_block(const int* __restrict__ counts, int* __restrict__ blockSums)
{
    __shared__ int sd[256];
    int t = threadIdx.x, base = blockIdx.x * 1024 + t * 4;
    int s = 0;
#pragma unroll
    for (int j = 0; j < 4; ++j) { int i = base + j; if (i < N_NODES) s += counts[i]; }
    sd[t] = s; __syncthreads();
    for (int off = 128; off; off >>= 1) {
        if (t < off) sd[t] += sd[t + off];
        __syncthreads();
    }
    if (t == 0) blockSums[blockIdx.x] = sd[0];
}

// ---------------------------------------------------------------------------
// 3) exclusive scan of the 196 block sums — one block, parallel (was serial).
// ---------------------------------------------------------------------------
__global__ void scan_tops(int* __restrict__ blockSums)
{
    __shared__ int sd[256];
    int t = threadIdx.x;
    int v = (t < SCAN_BLK) ? blockSums[t] : 0;
    sd[t] = v; __syncthreads();
    for (int off = 1; off < 256; off <<= 1) {
        int x = (t >= off) ? sd[t - off] : 0;
        __syncthreads();
        sd[t] += x;
        __syncthreads();
    }
    if (t < SCAN_BLK) blockSums[t] = sd[t] - v;   // exclusive
}

// ---------------------------------------------------------------------------
// 4) final scan: per-block exclusive scan + block offset -> offsets, cursor
// ---------------------------------------------------------------------------
__global__ void scan_final(const int* __restrict__ counts, const int* __restrict__ blockSums,
                           int* __restrict__ offsets, int* __restrict__ cursor)
{
    __shared__ int sd[256];
    int t = threadIdx.x, base = blockIdx.x * 1024 + t * 4;
    int c[4];
#pragma unroll
    for (int j = 0; j < 4; ++j) { int i = base + j; c[j] = (i < N_NODES) ? counts[i] : 0; }
    int tsum = c[0] + c[1] + c[2] + c[3];
    sd[t] = tsum; __syncthreads();
    for (int off = 1; off < 256; off <<= 1) {
        int x = (t >= off) ? sd[t - off] : 0;
        __syncthreads();
        sd[t] += x;
        __syncthreads();
    }
    int excl = sd[t] - tsum + blockSums[blockIdx.x];
#pragma unroll
    for (int j = 0; j < 4; ++j) {
        int i = base + j;
        if (i < N_NODES) { offsets[i] = excl; cursor[i] = excl; }
        excl += c[j];
    }
}

// ---------------------------------------------------------------------------
// 5) scatter event indices into CSR order
// ---------------------------------------------------------------------------
__global__ void scatter(const int* __restrict__ ids, int* __restrict__ cursor,
                        int* __restrict__ perm)
{
    int e = blockIdx.x * blockDim.x + threadIdx.x;
    if (e < E_EVENTS) {
        int pos = atomicAdd(cursor + ids[e], 1);
        perm[pos] = e;
    }
}

// ---------------------------------------------------------------------------
// 6) FUSED fat kernel: seg_reduce (gather, latency-bound) interleaved 4:1 with
//    attn_logits (stream, BW-bound) so they overlap on the machine.
//    grid = 12500 groups of 5 blocks: r=0..3 -> seg (4 nodes each), r=4 -> attn.
// ---------------------------------------------------------------------------
__global__ void __launch_bounds__(256, 8)
seg_attn(const int* __restrict__ perm, const int* __restrict__ offsets,
         const int* __restrict__ counts,
         const float* __restrict__ message, const float* __restrict__ ts,
         const float* __restrict__ nei1, const float* __restrict__ nei2,
         float* __restrict__ msg_out, float* __restrict__ t_out,
         float* __restrict__ logits)
{
    int g = blockIdx.x / 5, r = blockIdx.x % 5;
    int wid  = threadIdx.x >> 6;
    int lane = threadIdx.x & 63;

    if (r < 4) {
        // ---------------- segment gather-reduce: one wave per node -------------
        int n = (g * 4 + r) * 4 + wid;            // covers 200000 exactly
        int start = offsets[n];
        int len   = counts[n];
        const float2* msg2 = reinterpret_cast<const float2*>(message);
        float2 a0 = make_float2(0.f, 0.f), a1 = make_float2(0.f, 0.f);
        float tmax = 0.f;
        for (int base = 0; base < len; base += 64) {
            int cl = min(len - base, 64);
            // lane-parallel prefetch of perm + ts
            int   e_l = 0;
            float t_l = 0.f;
            if (lane < cl) {
                e_l = perm[start + base + lane];
                t_l = ts[e_l];
            }
            tmax = fmaxf(tmax, t_l);
            int i = 0;
            for (; i + 4 <= cl; i += 4) {
                int e0 = __shfl(e_l, i);
                int e1 = __shfl(e_l, i + 1);
                int e2 = __shfl(e_l, i + 2);
                int e3 = __shfl(e_l, i + 3);
                float2 m0 = msg2[(size_t)e0 * 64 + lane];
                float2 m1 = msg2[(size_t)e1 * 64 + lane];
                float2 m2 = msg2[(size_t)e2 * 64 + lane];
                float2 m3 = msg2[(size_t)e3 * 64 + lane];
                a0.x += m0.x; a0.y += m0.y;
                a1.x += m1.x; a1.y += m1.y;
                a0.x += m2.x; a0.y += m2.y;
                a1.x += m3.x; a1.y += m3.y;
            }
            for (; i < cl; ++i) {
                int e = __shfl(e_l, i);
                float2 m = msg2[(size_t)e * 64 + lane];
                a0.x += m.x; a0.y += m.y;
            }
        }
        float inv = 1.0f / (float)max(len, 1);
        float2 acc = make_float2((a0.x + a1.x) * inv, (a0.y + a1.y) * inv);
        reinterpret_cast<float2*>(msg_out)[(size_t)n * 64 + lane] = acc;
        // wave max of tmax
#pragma unroll
        for (int off = 32; off; off >>= 1) tmax = fmaxf(tmax, __shfl_xor(tmax, off));
        if (lane == 0) t_out[n] = tmax;
    } else {
        // ---------------- attention logits: one wave per b ---------------------
        int b = g * 4 + wid;                      // covers 50000 exactly
        int d4   = lane & 31;
        int half = lane >> 5;
        const float4* n2 = reinterpret_cast<const float4*>(nei2) + (size_t)b * (K_NEI * 32);
        float4 acc = make_float4(0.f, 0.f, 0.f, 0.f);
#pragma unroll
        for (int i = 0; i < K_NEI / 2; ++i) {
            float4 v = n2[(2 * i + half) * 32 + d4];
            acc.x += v.x; acc.y += v.y; acc.z += v.z; acc.w += v.w;
        }
        float4 s4;
        s4.x = acc.x + __shfl_xor(acc.x, 32);
        s4.y = acc.y + __shfl_xor(acc.y, 32);
        s4.z = acc.z + __shfl_xor(acc.z, 32);
        s4.w = acc.w + __shfl_xor(acc.w, 32);

        const float4* n1 = reinterpret_cast<const float4*>(nei1) + (size_t)b * (K_NEI * 32);
#pragma unroll
        for (int i = 0; i < K_NEI / 2; ++i) {
            int k = 2 * i + half;
            float4 v = n1[k * 32 + d4];
            float p = v.x * s4.x + v.y * s4.y + v.z * s4.z + v.w * s4.w;
#pragma unroll
            for (int off = 16; off; off >>= 1) p += __shfl_xor(p, off);
            if (d4 == 0) logits[(size_t)b * K_NEI + k] = p;
        }
    }
}

// ---------------------------------------------------------------------------
// 7) per-block online softmax partials over dim 0 (b). 128 blocks.
// ---------------------------------------------------------------------------
__global__ void softmax_partial(const float* __restrict__ logits, float2* __restrict__ partials)
{
    int t = threadIdx.x;
    float m[K_NEI], s[K_NEI];
#pragma unroll
    for (int k = 0; k < K_NEI; ++k) { m[k] = -INFINITY; s[k] = 0.f; }

    for (int b = blockIdx.x * 256 + t; b < B_BATCH; b += 128 * 256) {
        const float4* row = reinterpret_cast<const float4*>(logits + (size_t)b * K_NEI);
        float v[K_NEI];
#pragma unroll
        for (int q = 0; q < 5; ++q) {
            float4 rr = row[q];
            v[q * 4 + 0] = rr.x; v[q * 4 + 1] = rr.y; v[q * 4 + 2] = rr.z; v[q * 4 + 3] = rr.w;
        }
#pragma unroll
        for (int k = 0; k < K_NEI; ++k) {
            float nm = fmaxf(m[k], v[k]);
            s[k] = s[k] * expf(m[k] - nm) + expf(v[k] - nm);
            m[k] = nm;
        }
    }
#pragma unroll
    for (int k = 0; k < K_NEI; ++k) {
#pragma unroll
        for (int off = 32; off; off >>= 1) {
            float om = __shfl_xor(m[k], off);
            float os = __shfl_xor(s[k], off);
            float nm = fmaxf(m[k], om);
            s[k] = s[k] * expf(m[k] - nm) + os * expf(om - nm);
            m[k] = nm;
        }
    }
    __shared__ float lm[4][K_NEI], lsum[4][K_NEI];
    int wid = t >> 6, lane = t & 63;
    if (lane == 0) {
#pragma unroll
        for (int k = 0; k < K_NEI; ++k) { lm[wid][k] = m[k]; lsum[wid][k] = s[k]; }
    }
    __syncthreads();
    if (t < K_NEI) {
        float mm = lm[0][t], ss = lsum[0][t];
#pragma unroll
        for (int w = 1; w < 4; ++w) {
            float om = lm[w][t], os = lsum[w][t];
            float nm = fmaxf(mm, om);
            ss = ss * expf(mm - nm) + os * expf(om - nm);
            mm = nm;
        }
        partials[blockIdx.x * K_NEI + t] = make_float2(mm, ss);
    }
}

// ---------------------------------------------------------------------------
// 8) combine 128 partials -> stats[k]
// ---------------------------------------------------------------------------
__global__ void softmax_final(const float2* __restrict__ partials, float2* __restrict__ stats)
{
    int t = threadIdx.x;
    if (t < K_NEI) {
        float mm = -INFINITY, ss = 0.f;
        for (int i = 0; i < 128; ++i) {
            float2 p = partials[i * K_NEI + t];
            float nm = fmaxf(mm, p.x);
            ss = ss * expf(mm - nm) + p.y * expf(p.x - nm);
            mm = nm;
        }
        stats[t] = make_float2(mm, ss);
    }
}

// ---------------------------------------------------------------------------
// 9) normalize logits -> softmax scores
// ---------------------------------------------------------------------------
__global__ void softmax_norm(float* __restrict__ score, const float2* __restrict__ stats)
{
    int i = blockIdx.x * blockDim.x + threadIdx.x;
    if (i >= B_BATCH * K_NEI) return;
    int k = i % K_NEI;
    float2 st = stats[k];
    score[i] = expf(score[i] - st.x) / st.y;
}

extern "C" void kernel_launch(void* const* d_in, const int* in_sizes, int n_in,
                              void* d_out, int out_size, void* d_ws, size_t ws_size,
                              hipStream_t stream)
{
    const int*   node_ids = (const int*)  d_in[0];
    const float* message  = (const float*)d_in[1];
    const float* ts       = (const float*)d_in[2];
    const float* nei1     = (const float*)d_in[3];
    const float* nei2     = (const float*)d_in[4];

    float* out     = (float*)d_out;
    float* msg_out = out;                                   // [N,128]
    float* t_out   = out + (size_t)N_NODES * D_DIM;         // [N]
    float* score   = t_out + N_NODES;                       // [B,K]

    int*    wsi       = (int*)d_ws;
    int*    counts    = wsi;
    int*    offsets   = wsi + 200000;
    int*    cursor    = wsi + 400000;
    int*    blockSums = wsi + 600000;
    int*    perm      = wsi + 600320;
    float2* stats     = (float2*)(wsi + 1600320);
    float2* partials  = (float2*)(wsi + 1600384);

    hipMemsetAsync(counts, 0, (size_t)N_NODES * sizeof(int), stream);

    hist<<<(E_EVENTS + 255) / 256, 256, 0, stream>>>(node_ids, counts);
    scan_block<<<SCAN_BLK, 256, 0, stream>>>(counts, blockSums);
    scan_tops<<<1, 256, 0, stream>>>(blockSums);
    scan_final<<<SCAN_BLK, 256, 0, stream>>>(counts, blockSums, offsets, cursor);
    scatter<<<(E_EVENTS + 255) / 256, 256, 0, stream>>>(node_ids, cursor, perm);

    seg_attn<<<12500 * 5, 256, 0, stream>>>(
        perm, offsets, counts, message, ts, nei1, nei2, msg_out, t_out, score);

    softmax_partial<<<128, 256, 0, stream>>>(score, partials);
    softmax_final<<<1, 64, 0, stream>>>(partials, stats);
    softmax_norm<<<(B_BATCH * K_NEI + 255) / 256, 256, 0, stream>>>(score, stats);
}